// Round 1
// baseline (485.324 us; speedup 1.0000x reference)
//
#include <hip/hip_runtime.h>
#include <hip/hip_bf16.h>
#include <math.h>

#define NB 2
#define SEQ 1024
#define DM 768
#define NHEAD 12
#define HDIM 64
#define NEXP 8
#define FF 3072
#define NTOK (NB*SEQ)          // 2048
#define TDIM (3*DM)            // 2304
#define LNEPS 1e-5f
#define NSLOT (NTOK*2)         // 4096

typedef __attribute__((ext_vector_type(8))) short v8s;
typedef __attribute__((ext_vector_type(4))) float v4f;

// async global->LDS, 16B per lane; dst wave-uniform base (lane*16 added by HW)
#define GLDS16(src, dst) \
    __builtin_amdgcn_global_load_lds((const __attribute__((address_space(1))) unsigned int*)(src), \
                                     (__attribute__((address_space(3))) unsigned int*)(dst), 16, 0, 0)

// raw barrier with compiler memory fences on both sides (no vmcnt(0) drain!)
#define BARF() do { asm volatile("" ::: "memory"); __builtin_amdgcn_s_barrier(); asm volatile("" ::: "memory"); } while(0)
#define WAITV(n) asm volatile("s_waitcnt vmcnt(" #n ")" ::: "memory")

static __device__ __forceinline__ float bf2f(unsigned short u){
    return __uint_as_float(((unsigned)u) << 16);
}
static __device__ __forceinline__ unsigned short f2bf(float f){
    unsigned u = __float_as_uint(f);
    u += 0x7fffu + ((u >> 16) & 1u);   // RNE
    return (unsigned short)(u >> 16);
}
static __device__ __forceinline__ float gelu_exact(float x){
    return 0.5f * x * (1.0f + erff(x * 0.70710678118654752440f));
}

// ---------------- transpose+convert: in fp32 [R][C] -> out bf16 [C][R], per z slice ----------------
__global__ __launch_bounds__(256) void tconv_kernel(const float* __restrict__ in,
                                                    unsigned short* __restrict__ out,
                                                    int R, int C){
    __shared__ float T[32][33];
    size_t base = (size_t)blockIdx.z * R * C;
    int c0 = blockIdx.x * 32, r0 = blockIdx.y * 32;
    int t = threadIdx.x;
    int tr = t >> 3, tc4 = (t & 7) * 4;
    float4 v = *(const float4*)&in[base + (size_t)(r0 + tr) * C + c0 + tc4];
    T[tr][tc4+0] = v.x; T[tr][tc4+1] = v.y; T[tr][tc4+2] = v.z; T[tr][tc4+3] = v.w;
    __syncthreads();
    int oc = t >> 3, or4 = (t & 7) * 4;
    ushort4 o;
    o.x = f2bf(T[or4+0][oc]); o.y = f2bf(T[or4+1][oc]);
    o.z = f2bf(T[or4+2][oc]); o.w = f2bf(T[or4+3][oc]);
    *(ushort4*)&out[base + (size_t)(c0 + oc) * R + r0 + or4] = o;
}

// ---------------- LayerNorm (bf16 out only) ----------------
__global__ __launch_bounds__(256) void ln_b(const float* __restrict__ in,
                                            const float* __restrict__ g,
                                            const float* __restrict__ b,
                                            unsigned short* __restrict__ outb){
    int t = blockIdx.x;
    const float* row = in + (size_t)t * DM;
    int tid = threadIdx.x;
    float v0 = row[tid], v1 = row[tid + 256], v2 = row[tid + 512];
    float s  = v0 + v1 + v2;
    float ss = v0*v0 + v1*v1 + v2*v2;
    for (int off = 32; off; off >>= 1){
        s  += __shfl_down(s, off);
        ss += __shfl_down(ss, off);
    }
    __shared__ float ls[4], lss[4];
    int wid = tid >> 6, lane = tid & 63;
    if (lane == 0){ ls[wid] = s; lss[wid] = ss; }
    __syncthreads();
    if (tid == 0){
        float a = ls[0] + ls[1] + ls[2] + ls[3];
        float c = lss[0] + lss[1] + lss[2] + lss[3];
        float mu = a / (float)DM;
        float var = c / (float)DM - mu * mu;
        ls[0] = mu; lss[0] = rsqrtf(var + LNEPS);
    }
    __syncthreads();
    float mu = ls[0], rs = lss[0];
    unsigned short* obrow = outb + (size_t)t * DM;
    obrow[tid]     = f2bf((v0 - mu) * rs * g[tid]       + b[tid]);
    obrow[tid+256] = f2bf((v1 - mu) * rs * g[tid + 256] + b[tid + 256]);
    obrow[tid+512] = f2bf((v2 - mu) * rs * g[tid + 512] + b[tid + 512]);
}

// ---------------- LayerNorm + router fused: bf16 out + top-2 expert routing ----------------
__global__ __launch_bounds__(256) void ln_router(const float* __restrict__ in,
                                                 const float* __restrict__ g,
                                                 const float* __restrict__ b,
                                                 const float* __restrict__ wr,
                                                 unsigned short* __restrict__ outb,
                                                 int* __restrict__ cnt,
                                                 int* __restrict__ expTok,
                                                 int* __restrict__ tokE,
                                                 int* __restrict__ tokPos,
                                                 float* __restrict__ tokGate){
    int t = blockIdx.x;
    const float* row = in + (size_t)t * DM;
    int tid = threadIdx.x;
    float v0 = row[tid], v1 = row[tid + 256], v2 = row[tid + 512];
    float s  = v0 + v1 + v2;
    float ss = v0*v0 + v1*v1 + v2*v2;
    for (int off = 32; off; off >>= 1){
        s  += __shfl_down(s, off);
        ss += __shfl_down(ss, off);
    }
    __shared__ float ls[4], lss[4];
    __shared__ float wsum[4][NEXP];
    int wid = tid >> 6, lane = tid & 63;
    if (lane == 0){ ls[wid] = s; lss[wid] = ss; }
    __syncthreads();
    if (tid == 0){
        float a = ls[0] + ls[1] + ls[2] + ls[3];
        float c = lss[0] + lss[1] + lss[2] + lss[3];
        float mu = a / (float)DM;
        float var = c / (float)DM - mu * mu;
        ls[0] = mu; lss[0] = rsqrtf(var + LNEPS);
    }
    __syncthreads();
    float mu = ls[0], rs = lss[0];
    float o0 = (v0 - mu) * rs * g[tid]       + b[tid];
    float o1 = (v1 - mu) * rs * g[tid + 256] + b[tid + 256];
    float o2 = (v2 - mu) * rs * g[tid + 512] + b[tid + 512];
    unsigned short* obrow = outb + (size_t)t * DM;
    obrow[tid] = f2bf(o0); obrow[tid+256] = f2bf(o1); obrow[tid+512] = f2bf(o2);
    float p[NEXP];
    #pragma unroll
    for (int e = 0; e < NEXP; e++)
        p[e] = o0*wr[e*DM + tid] + o1*wr[e*DM + tid + 256] + o2*wr[e*DM + tid + 512];
    #pragma unroll
    for (int e = 0; e < NEXP; e++)
        for (int off = 32; off; off >>= 1) p[e] += __shfl_down(p[e], off);
    if (lane == 0){
        #pragma unroll
        for (int e = 0; e < NEXP; e++) wsum[wid][e] = p[e];
    }
    __syncthreads();
    if (tid == 0){
        float lg[NEXP];
        #pragma unroll
        for (int e = 0; e < NEXP; e++)
            lg[e] = wsum[0][e] + wsum[1][e] + wsum[2][e] + wsum[3][e];
        int i0 = 0; float m0 = lg[0];
        #pragma unroll
        for (int e = 1; e < NEXP; e++) if (lg[e] > m0){ m0 = lg[e]; i0 = e; }
        int i1 = -1; float m1 = -INFINITY;
        #pragma unroll
        for (int e = 0; e < NEXP; e++) if (e != i0 && lg[e] > m1){ m1 = lg[e]; i1 = e; }
        float mx = fmaxf(m0, m1);
        float e0 = __expf(m0 - mx), e1 = __expf(m1 - mx);
        float inv = 1.0f / (e0 + e1);
        int p0 = atomicAdd(&cnt[i0], 1);
        int p1 = atomicAdd(&cnt[i1], 1);
        expTok[i0*NTOK + p0] = t;
        expTok[i1*NTOK + p1] = t;
        tokE[t*2]   = i0; tokE[t*2+1]   = i1;
        tokPos[t*2] = p0; tokPos[t*2+1] = p1;
        tokGate[t*2]   = e0 * inv;
        tokGate[t*2+1] = e1 * inv;
    }
}

// ---------------- QKV GEMM (64x128 tile, dbuf pipelined) + fused attn prep epilogue ----------------
// A = xb [2048][768], B = Wab [2304][768]; writes Qb/Kb [bh][s][64] bf16, Vt [bh][d][s] bf16
__global__ __launch_bounds__(256) void mm_qkv(const unsigned short* __restrict__ Ab,
                                              const unsigned short* __restrict__ Bb,
                                              const float* __restrict__ bias,
                                              unsigned short* __restrict__ Qb,
                                              unsigned short* __restrict__ Kb,
                                              unsigned short* __restrict__ Vt){
    __shared__ __align__(16) unsigned short As[2][64*32];
    __shared__ __align__(16) unsigned short Bs[2][128*32];
    int bm = blockIdx.y * 64, bn = blockIdx.x * 128;
    int tid = threadIdx.x, wave = tid >> 6, lane = tid & 63;
    int quad = lane >> 4, l15 = lane & 15;
    int wm = wave >> 1, wn = wave & 1;
    int arow = tid >> 2, achunk = (tid & 3) * 8;
    int lrow = lane >> 2, lchunk = (lane & 3) * 8;
    const unsigned short* aS  = Ab + (size_t)(bm + arow) * DM + achunk;
    const unsigned short* bS0 = Bb + (size_t)(bn +      wave*16 + lrow) * DM + lchunk;
    const unsigned short* bS1 = Bb + (size_t)(bn + 64 + wave*16 + lrow) * DM + lchunk;
    v4f acc[2][4];
    #pragma unroll
    for (int i = 0; i < 2; i++)
        #pragma unroll
        for (int j = 0; j < 4; j++) acc[i][j] = (v4f){0.f,0.f,0.f,0.f};

#define QKV_STAGE(buf, kb) do { \
    GLDS16(aS  + (kb), &As[buf][(wave*16)*32]); \
    GLDS16(bS0 + (kb), &Bs[buf][(     wave*16)*32]); \
    GLDS16(bS1 + (kb), &Bs[buf][(64 + wave*16)*32]); \
} while(0)
#define QKV_COMP(buf) do { \
    v8s a[2], bfr[4]; \
    _Pragma("unroll") \
    for (int i = 0; i < 2; i++) a[i] = *(const v8s*)&As[buf][(wm*32 + i*16 + l15)*32 + quad*8]; \
    _Pragma("unroll") \
    for (int i = 0; i < 4; i++) bfr[i] = *(const v8s*)&Bs[buf][(wn*64 + i*16 + l15)*32 + quad*8]; \
    _Pragma("unroll") \
    for (int mi = 0; mi < 2; mi++) \
        _Pragma("unroll") \
        for (int ni = 0; ni < 4; ni++) \
            acc[mi][ni] = __builtin_amdgcn_mfma_f32_16x16x32_bf16(a[mi], bfr[ni], acc[mi][ni], 0, 0, 0); \
} while(0)

    const int NK = DM/32;   // 24 (even)
    QKV_STAGE(0, 0);
    #pragma unroll 1
    for (int kt = 0; kt < NK; kt += 2){
        QKV_STAGE(1, (kt+1)*32);
        WAITV(3);
        BARF();
        QKV_COMP(0);
        BARF();
        if (kt + 2 < NK){ QKV_STAGE(0, (kt+2)*32); WAITV(3); }
        else            { WAITV(0); }
        BARF();
        QKV_COMP(1);
        BARF();
    }
    int btyp = bn / DM;   // 0=Q, 1=K, 2=V (128 | 768)
    #pragma unroll
    for (int ni = 0; ni < 4; ni++){
        int n = bn + wn*64 + ni*16 + l15;
        float bb = bias[n];
        int hd = n % DM; int h = hd >> 6; int d = hd & 63;
        #pragma unroll
        for (int mi = 0; mi < 2; mi++){
            int m = bm + wm*32 + mi*16 + quad*4;
            int b = m >> 10, sd = m & 1023;
            size_t bhbase = (size_t)(b*NHEAD + h);
            if (btyp == 0){
                #pragma unroll
                for (int r = 0; r < 4; r++)
                    Qb[(bhbase*SEQ + sd + r)*HDIM + d] = f2bf((acc[mi][ni][r] + bb) * 0.125f);
            } else if (btyp == 1){
                #pragma unroll
                for (int r = 0; r < 4; r++)
                    Kb[(bhbase*SEQ + sd + r)*HDIM + d] = f2bf(acc[mi][ni][r] + bb);
            } else {
                ushort4 o;
                o.x = f2bf(acc[mi][ni][0] + bb); o.y = f2bf(acc[mi][ni][1] + bb);
                o.z = f2bf(acc[mi][ni][2] + bb); o.w = f2bf(acc[mi][ni][3] + bb);
                *(ushort4*)&Vt[(bhbase*HDIM + d)*SEQ + sd] = o;
            }
        }
    }
}

// ---------------- Flash attention: one wave per (bh, 32-query tile) ----------------
__global__ __launch_bounds__(64) void fattn(const unsigned short* __restrict__ Qb,
                                            const unsigned short* __restrict__ Kb,
                                            const unsigned short* __restrict__ Vt,
                                            unsigned short* __restrict__ ctxb){
    int bh = blockIdx.x >> 5;
    int q0 = (31 - (blockIdx.x & 31)) * 32;   // long tiles first
    int h = bh % NHEAD, b = bh / NHEAD;
    int lane = threadIdx.x;
    int quad = lane >> 4, l15 = lane & 15;

    __shared__ __align__(16) unsigned short Plds[32*32];

    const unsigned short* qp = Qb + ((size_t)bh*SEQ + q0 + l15) * HDIM + quad*8;
    v8s qa00 = *(const v8s*)qp;
    v8s qa01 = *(const v8s*)(qp + 32);
    v8s qa10 = *(const v8s*)(qp + 16*HDIM);
    v8s qa11 = *(const v8s*)(qp + 16*HDIM + 32);

    v4f o[2][4];
    #pragma unroll
    for (int i = 0; i < 2; i++)
        #pragma unroll
        for (int j = 0; j < 4; j++) o[i][j] = (v4f){0.f,0.f,0.f,0.f};
    float mrow[2][4], lrow[2][4];
    #pragma unroll
    for (int i = 0; i < 2; i++)
        #pragma unroll
        for (int r = 0; r < 4; r++){ mrow[i][r] = -1e30f; lrow[i][r] = 0.f; }

    int nch = (q0 >> 5) + 1;
    for (int ch = 0; ch < nch; ch++){
        int kt = ch * 32;
        const unsigned short* kp = Kb + ((size_t)bh*SEQ + kt + l15) * HDIM + quad*8;
        v8s k00 = *(const v8s*)kp;
        v8s k01 = *(const v8s*)(kp + 32);
        v8s k10 = *(const v8s*)(kp + 16*HDIM);
        v8s k11 = *(const v8s*)(kp + 16*HDIM + 32);
        v4f s00 = {0,0,0,0}, s01 = {0,0,0,0}, s10 = {0,0,0,0}, s11 = {0,0,0,0};
        s00 = __builtin_amdgcn_mfma_f32_16x16x32_bf16(qa00, k00, s00, 0, 0, 0);
        s00 = __builtin_amdgcn_mfma_f32_16x16x32_bf16(qa01, k01, s00, 0, 0, 0);
        s01 = __builtin_amdgcn_mfma_f32_16x16x32_bf16(qa00, k10, s01, 0, 0, 0);
        s01 = __builtin_amdgcn_mfma_f32_16x16x32_bf16(qa01, k11, s01, 0, 0, 0);
        s10 = __builtin_amdgcn_mfma_f32_16x16x32_bf16(qa10, k00, s10, 0, 0, 0);
        s10 = __builtin_amdgcn_mfma_f32_16x16x32_bf16(qa11, k01, s10, 0, 0, 0);
        s11 = __builtin_amdgcn_mfma_f32_16x16x32_bf16(qa10, k10, s11, 0, 0, 0);
        s11 = __builtin_amdgcn_mfma_f32_16x16x32_bf16(qa11, k11, s11, 0, 0, 0);

        int key0 = kt + l15, key1 = kt + 16 + l15;
        float alpha[2][4];
        #pragma unroll
        for (int mi = 0; mi < 2; mi++){
            #pragma unroll
            for (int r = 0; r < 4; r++){
                int qrow = q0 + mi*16 + quad*4 + r;
                float sv0 = mi ? s10[r] : s00[r];
                float sv1 = mi ? s11[r] : s01[r];
                float v0 = (key0 <= qrow) ? sv0 : -1e30f;
                float v1 = (key1 <= qrow) ? sv1 : -1e30f;
                float mx = fmaxf(v0, v1);
                mx = fmaxf(mx, __shfl_xor(mx, 1));
                mx = fmaxf(mx, __shfl_xor(mx, 2));
                mx = fmaxf(mx, __shfl_xor(mx, 4));
                mx = fmaxf(mx, __shfl_xor(mx, 8));
                float mn = fmaxf(mrow[mi][r], mx);
                alpha[mi][r] = __expf(mrow[mi][r] - mn);
                float p0 = __expf(v0 - mn);
                float p1 = __expf(v1 - mn);
                float ps = p0 + p1;
                ps += __shfl_xor(ps, 1);
                ps += __shfl_xor(ps, 2);
                ps += __shfl_xor(ps, 4);
                ps += __shfl_xor(ps, 8);
                lrow[mi][r] = lrow[mi][r] * alpha[mi][r] + ps;
                mrow[mi][r] = mn;
                Plds[(mi*16 + quad*4 + r)*32 + l15]      = f2bf(p0);
                Plds[(mi*16 + quad*4 + r)*32 + 16 + l15] = f2bf(p1);
            }
        }
        #pragma unroll
        for (int mi = 0; mi < 2; mi++)
            #pragma unroll
            for (int df = 0; df < 4; df++)
                #pragma unroll
                for (int r = 0; r < 4; r++)
                    o[mi][df][r] *= alpha[mi][r];
        __syncthreads();
        v8s pa0 = *(const v8s*)&Plds[l15*32 + quad*8];
        v8s pa1 = *(const v8s*)&Plds[(16 + l15)*32 + quad*8];
        const unsigned short* vp = Vt + ((size_t)bh*HDIM + l15) * SEQ + kt + quad*8;
        #pragma unroll
        for (int df = 0; df < 4; df++){
            v8s vb = *(const v8s*)(vp + df*16*SEQ);
            o[0][df] = __builtin_amdgcn_mfma_f32_16x16x32_bf16(pa0, vb, o[0][df], 0, 0, 0);
            o[1][df] = __builtin_amdgcn_mfma_f32_16x16x32_bf16(pa1, vb, o[1][df], 0, 0, 0);
        }
        __syncthreads();
    }
    #pragma unroll
    for (int mi = 0; mi < 2; mi++){
        #pragma unroll
        for (int r = 0; r < 4; r++){
            float inv = 1.0f / lrow[mi][r];
            size_t orow = (size_t)(b*SEQ + q0 + mi*16 + quad*4 + r) * DM + h*HDIM;
            #pragma unroll
            for (int df = 0; df < 4; df++)
                ctxb[orow + df*16 + l15] = f2bf(o[mi][df][r] * inv);
        }
    }
}

// ---------------- attn-proj GEMM (64x64 tile, dbuf pipelined) + bias + residual -> hs fp32 ----------------
__global__ __launch_bounds__(256) void mm_attnproj(const unsigned short* __restrict__ Ab,
                                                   const unsigned short* __restrict__ Bb,
                                                   const float* __restrict__ bias,
                                                   const float* __restrict__ res,
                                                   float* __restrict__ C){
    __shared__ __align__(16) unsigned short As[2][64*32];
    __shared__ __align__(16) unsigned short Bs[2][64*32];
    int bm = blockIdx.y * 64, bn = blockIdx.x * 64;
    int tid = threadIdx.x, wave = tid >> 6, lane = tid & 63;
    int quad = lane >> 4, l15 = lane & 15;
    int wm = wave >> 1, wn = wave & 1;
    int arow = tid >> 2, achunk = (tid & 3) * 8;
    const unsigned short* aS = Ab + (size_t)(bm + arow) * DM + achunk;
    const unsigned short* bS = Bb + (size_t)(bn + arow) * DM + achunk;
    v4f acc[2][2];
    #pragma unroll
    for (int i = 0; i < 2; i++)
        #pragma unroll
        for (int j = 0; j < 2; j++) acc[i][j] = (v4f){0.f,0.f,0.f,0.f};

#define AP_STAGE(buf, kb) do { \
    GLDS16(aS + (kb), &As[buf][(wave*16)*32]); \
    GLDS16(bS + (kb), &Bs[buf][(wave*16)*32]); \
} while(0)
#define AP_COMP(buf) do { \
    v8s a[2], bfr[2]; \
    _Pragma("unroll") \
    for (int i = 0; i < 2; i++){ \
        a[i]   = *(const v8s*)&As[buf][(wm*32 + i*16 + l15)*32 + quad*8]; \
        bfr[i] = *(const v8s*)&Bs[buf][(wn*32 + i*16 + l15)*32 + quad*8]; \
    } \
    _Pragma("unroll") \
    for (int mi = 0; mi < 2; mi++) \
        _Pragma("unroll") \
        for (int ni = 0; ni < 2; ni++) \
            acc[mi][ni] = __builtin_amdgcn_mfma_f32_16x16x32_bf16(a[mi], bfr[ni], acc[mi][ni], 0, 0, 0); \
} while(0)

    const int NK = DM/32;   // 24 (even)
    AP_STAGE(0, 0);
    #pragma unroll 1
    for (int kt = 0; kt < NK; kt += 2){
        AP_STAGE(1, (kt+1)*32);
        WAITV(2);
        BARF();
        AP_COMP(0);
        BARF();
        if (kt + 2 < NK){ AP_STAGE(0, (kt+2)*32); WAITV(2); }
        else            { WAITV(0); }
        BARF();
        AP_COMP(1);
        BARF();
    }
    #pragma unroll
    for (int ni = 0; ni < 2; ni++){
        int n = bn + wn*32 + ni*16 + l15;
        float bb = bias[n];
        #pragma unroll
        for (int mi = 0; mi < 2; mi++){
            int m = bm + wm*32 + mi*16 + quad*4;
            #pragma unroll
            for (int r = 0; r < 4; r++)
                C[(size_t)(m + r) * DM + n] = acc[mi][ni][r] + bb + res[(size_t)(m + r) * DM + n];
        }
    }
}

// ---------------- MoE fc (128x128 tile, dbuf pipelined): gathered xb rows @ Wfcb[e] + bias, gelu -> H bf16 ----------------
__global__ __launch_bounds__(256) void mm_fc(const unsigned short* __restrict__ Xb,
                                             const unsigned short* __restrict__ Wb,
                                             const float* __restrict__ bfc,
                                             const int* __restrict__ expTok,
                                             const int* __restrict__ cnt,
                                             const int* __restrict__ offE,
                                             unsigned short* __restrict__ H){
    int e = blockIdx.z, tile = blockIdx.y;
    int c = cnt[e];
    int rows = c - tile * 128;
    if (rows <= 0) return;
    __shared__ __align__(16) unsigned short As[2][128*32];
    __shared__ __align__(16) unsigned short Bs[2][128*32];
    __shared__ int toks[128];
    int bn = blockIdx.x * 128;
    int tid = threadIdx.x, wave = tid >> 6, lane = tid & 63;
    if (tid < 128){
        int idx = tile * 128 + tid;
        if (idx >= c) idx = c - 1;
        toks[tid] = expTok[e * NTOK + idx];
    }
    __syncthreads();
    int quad = lane >> 4, l15 = lane & 15;
    int wm = wave >> 1, wn = wave & 1;
    int lrow = lane >> 2, lchunk = (lane & 3) * 8;
    int tok0 = toks[     wave*16 + lrow];
    int tok1 = toks[64 + wave*16 + lrow];
    const unsigned short* Be = Wb + (size_t)e * FF * DM;
    const unsigned short* aS0 = Xb + (size_t)tok0 * DM + lchunk;
    const unsigned short* aS1 = Xb + (size_t)tok1 * DM + lchunk;
    const unsigned short* bS0 = Be + (size_t)(bn +      wave*16 + lrow) * DM + lchunk;
    const unsigned short* bS1 = Be + (size_t)(bn + 64 + wave*16 + lrow) * DM + lchunk;
    v4f acc[4][4];
    #pragma unroll
    for (int i = 0; i < 4; i++)
        #pragma unroll
        for (int j = 0; j < 4; j++) acc[i][j] = (v4f){0.f,0.f,0.f,0.f};

#define FC_STAGE(buf, kb) do { \
    GLDS16(aS0 + (kb), &As[buf][(     wave*16)*32]); \
    GLDS16(aS1 + (kb), &As[buf][(64 + wave*16)*32]); \
    GLDS16(bS0 + (kb), &Bs[buf][(     wave*16)*32]); \
    GLDS16(bS1 + (kb), &Bs[buf][(64 + wave*16)*32]); \
} while(0)
#define FC_COMP(buf) do { \
    v8s a[4], bfr[4]; \
    _Pragma("unroll") \
    for (int i = 0; i < 4; i++){ \
        a[i]   = *(const v8s*)&As[buf][(wm*64 + i*16 + l15)*32 + quad*8]; \
        bfr[i] = *(const v8s*)&Bs[buf][(wn*64 + i*16 + l15)*32 + quad*8]; \
    } \
    _Pragma("unroll") \
    for (int mt = 0; mt < 4; mt++) \
        _Pragma("unroll") \
        for (int nt = 0; nt < 4; nt++) \
            acc[mt][nt] = __builtin_amdgcn_mfma_f32_16x16x32_bf16(a[mt], bfr[nt], acc[mt][nt], 0, 0, 0); \
} while(0)

    const int NK = DM/32;   // 24 (even)
    FC_STAGE(0, 0);
    #pragma unroll 1
    for (int kt = 0; kt < NK; kt += 2){
        FC_STAGE(1, (kt+1)*32);
        WAITV(4);
        BARF();
        FC_COMP(0);
        BARF();
        if (kt + 2 < NK){ FC_STAGE(0, (kt+2)*32); WAITV(4); }
        else            { WAITV(0); }
        BARF();
        FC_COMP(1);
        BARF();
    }
    int slot0 = offE[e] + tile * 128;
    #pragma unroll
    for (int nt = 0; nt < 4; nt++){
        int n = bn + wn*64 + nt*16 + l15;
        float bb = bfc[(size_t)e * FF + n];
        #pragma unroll
        for (int mt = 0; mt < 4; mt++){
            int ml = wm*64 + mt*16 + quad*4;
            #pragma unroll
            for (int r = 0; r < 4; r++)
                if (ml + r < rows)
                    H[(size_t)(slot0 + ml + r) * FF + n] = f2bf(gelu_exact(acc[mt][nt][r] + bb));
        }
    }
}

// ---------------- MoE proj (64x128 tile, split-K=2, dbuf pipelined): H @ Wprb[e] -> Yp[sk] fp32 ----------------
__global__ __launch_bounds__(256) void mm_proj(const unsigned short* __restrict__ H,
                                               const unsigned short* __restrict__ Wb,
                                               const int* __restrict__ cnt,
                                               const int* __restrict__ offE,
                                               float* __restrict__ Yp){
    int e = blockIdx.z, tile = blockIdx.y;
    int c = cnt[e];
    int rows = c - tile * 64;
    if (rows <= 0) return;
    int sk = blockIdx.x & 1;
    int bn = (blockIdx.x >> 1) * 128;
    __shared__ __align__(16) unsigned short As[2][64*32];
    __shared__ __align__(16) unsigned short Bs[2][128*32];
    int tid = threadIdx.x, wave = tid >> 6, lane = tid & 63;
    int quad = lane >> 4, l15 = lane & 15;
    int wm = wave >> 1, wn = wave & 1;
    int slot0 = offE[e] + tile * 64;
    int arow = tid >> 2, achunk = (tid & 3) * 8;
    int arl = arow < rows ? arow : rows - 1;
    int lrow = lane >> 2, lchunk = (lane & 3) * 8;
    const unsigned short* Be = Wb + (size_t)e * DM * FF;
    const unsigned short* aS  = H  + (size_t)(slot0 + arl) * FF + sk*1536 + achunk;
    const unsigned short* bS0 = Be + (size_t)(bn +      wave*16 + lrow) * FF + sk*1536 + lchunk;
    const unsigned short* bS1 = Be + (size_t)(bn + 64 + wave*16 + lrow) * FF + sk*1536 + lchunk;
    v4f acc[2][4];
    #pragma unroll
    for (int i = 0; i < 2; i++)
        #pragma unroll
        for (int j = 0; j < 4; j++) acc[i][j] = (v4f){0.f,0.f,0.f,0.f};

#define PJ_STAGE(buf, kb) do { \
    GLDS16(aS  + (kb), &As[buf][(wave*16)*32]); \
    GLDS16(bS0 + (kb), &Bs[buf][(     wave*16)*32]); \
    GLDS16(bS1 + (kb), &Bs[buf][(64 + wave*16)*32]); \
} while(0)
#define PJ_COMP(buf) do { \
    v8s a[2], bfr[4]; \
    _Pragma("unroll") \
    for (int i = 0; i < 2; i++) a[i] = *(const v8s*)&As[buf][(wm*32 + i*16 + l15)*32 + quad*8]; \
    _Pragma("unroll") \
    for (int i = 0; i < 4; i++) bfr[i] = *(const v8s*)&Bs[buf][(wn*64 + i*16 + l15)*32 + quad*8]; \
    _Pragma("unroll") \
    for (int mi = 0; mi < 2; mi++) \
        _Pragma("unroll") \
        for (int ni = 0; ni < 4; ni++) \
            acc[mi][ni] = __builtin_amdgcn_mfma_f32_16x16x32_bf16(a[mi], bfr[ni], acc[mi][ni], 0, 0, 0); \
} while(0)

    const int NK = 1536/32;   // 48 (even)
    PJ_STAGE(0, 0);
    #pragma unroll 1
    for (int kt = 0; kt < NK; kt += 2){
        PJ_STAGE(1, (kt+1)*32);
        WAITV(3);
        BARF();
        PJ_COMP(0);
        BARF();
        if (kt + 2 < NK){ PJ_STAGE(0, (kt+2)*32); WAITV(3); }
        else            { WAITV(0); }
        BARF();
        PJ_COMP(1);
        BARF();
    }
    float* Yo = Yp + (size_t)sk * NSLOT * DM;
    #pragma unroll
    for (int ni = 0; ni < 4; ni++){
        int n = bn + wn*64 + ni*16 + l15;
        #pragma unroll
        for (int mi = 0; mi < 2; mi++){
            int ml = wm*32 + mi*16 + quad*4;
            #pragma unroll
            for (int r = 0; r < 4; r++)
                if (ml + r < rows)
                    Yo[(size_t)(slot0 + ml + r) * DM + n] = acc[mi][ni][r];
        }
    }
}

__global__ void offsets_kernel(const int* __restrict__ cnt, int* __restrict__ offE){
    if (threadIdx.x == 0 && blockIdx.x == 0){
        int a = 0;
        for (int e = 0; e < NEXP; e++){ offE[e] = a; a += cnt[e]; }
    }
}

// ---------------- Combine: out = hs + sum_k gate_k * (Yp0+Yp1 + b_proj[e_k]) ----------------
__global__ __launch_bounds__(256) void combine_kernel(const float* __restrict__ hs,
                                                      const float* __restrict__ Yp,
                                                      const float* __restrict__ bproj,
                                                      const int* __restrict__ tokE,
                                                      const int* __restrict__ tokPos,
                                                      const float* __restrict__ tokGate,
                                                      const int* __restrict__ offE,
                                                      float* __restrict__ out){
    int t = blockIdx.x;
    int e0 = tokE[t*2], e1 = tokE[t*2+1];
    int s0 = offE[e0] + tokPos[t*2];
    int s1 = offE[e1] + tokPos[t*2+1];
    float g0 = tokGate[t*2], g1 = tokGate[t*2+1];
    const float* y0a = Yp + (size_t)s0 * DM;
    const float* y0b = Yp + (size_t)NSLOT * DM + (size_t)s0 * DM;
    const float* y1a = Yp + (size_t)s1 * DM;
    const float* y1b = Yp + (size_t)NSLOT * DM + (size_t)s1 * DM;
    const float* b0 = bproj + (size_t)e0 * DM;
    const float* b1 = bproj + (size_t)e1 * DM;
    const float* hr = hs + (size_t)t * DM;
    float* orow = out + (size_t)t * DM;
    for (int d = threadIdx.x; d < DM; d += 256){
        orow[d] = hr[d] + g0 * (y0a[d] + y0b[d] + b0[d]) + g1 * (y1a[d] + y1b[d] + b1[d]);
    }
}

extern "C" void kernel_launch(void* const* d_in, const int* in_sizes, int n_in,
                              void* d_out, int out_size, void* d_ws, size_t ws_size,
                              hipStream_t stream){
    (void)in_sizes; (void)n_in; (void)out_size; (void)ws_size;
    const float* hidden  = (const float*)d_in[0];
    const float* ln1_g   = (const float*)d_in[1];
    const float* ln1_b   = (const float*)d_in[2];
    const float* w_attn  = (const float*)d_in[3];
    const float* b_attn  = (const float*)d_in[4];
    const float* w_aproj = (const float*)d_in[5];
    const float* b_aproj = (const float*)d_in[6];
    const float* ln2_g   = (const float*)d_in[7];
    const float* ln2_b   = (const float*)d_in[8];
    const float* w_rout  = (const float*)d_in[9];
    const float* w_fc    = (const float*)d_in[10];
    const float* b_fc    = (const float*)d_in[11];
    const float* w_proj  = (const float*)d_in[12];
    const float* b_proj  = (const float*)d_in[13];
    float* out = (float*)d_out;

    char* ws = (char*)d_ws;
    // layout (bytes):
    float*          hs   = (float*)(ws + 0);                      //  6,291,456
    unsigned short* xb   = (unsigned short*)(ws + 6291456);       //  3,145,728
    unsigned short* Qb   = (unsigned short*)(ws + 9437184);       //  3,145,728
    unsigned short* Kb   = (unsigned short*)(ws + 12582912);      //  3,145,728
    unsigned short* Vt   = (unsigned short*)(ws + 15728640);      //  3,145,728
    unsigned short* ctxb = (unsigned short*)(ws + 18874368);      //  3,145,728
    unsigned short* Wab  = (unsigned short*)(ws + 22020096);      //  3,538,944
    unsigned short* Wapb = (unsigned short*)(ws + 25559040);      //  1,179,648
    // H overlays Qb..Wapb (all dead by mm_fc) + fresh space up to 34,603,008
    unsigned short* H    = (unsigned short*)(ws + 9437184);       // 25,165,824 overlay
    unsigned short* Wfcb = (unsigned short*)(ws + 34603008);      // 37,748,736
    unsigned short* Wprb = (unsigned short*)(ws + 72351744);      // 37,748,736
    // Yp (2 split-K partials) overlays Wfcb (dead after mm_fc)
    float*          Yp   = (float*)(ws + 34603008);               // 25,165,824 overlay
    char* rt = ws + 110100480;
    int* cnt      = (int*)(rt + 0);
    int* offE     = (int*)(rt + 64);
    int* expTok   = (int*)(rt + 128);                   // 65,536
    int* tokE     = (int*)(rt + 128 + 65536);           // 16,384
    int* tokPos   = (int*)(rt + 128 + 81920);           // 16,384
    float* tokGate= (float*)(rt + 128 + 98304);         // 16,384

    hipMemsetAsync(cnt, 0, NEXP * sizeof(int), stream);

    // weight transpose+convert to bf16 [N][K]
    tconv_kernel<<<dim3(TDIM/32, DM/32, 1), 256, 0, stream>>>(w_attn, Wab, DM, TDIM);
    tconv_kernel<<<dim3(DM/32, DM/32, 1), 256, 0, stream>>>(w_aproj, Wapb, DM, DM);
    tconv_kernel<<<dim3(FF/32, DM/32, NEXP), 256, 0, stream>>>(w_fc, Wfcb, DM, FF);
    tconv_kernel<<<dim3(DM/32, FF/32, NEXP), 256, 0, stream>>>(w_proj, Wprb, FF, DM);

    ln_b<<<NTOK, 256, 0, stream>>>(hidden, ln1_g, ln1_b, xb);
    mm_qkv<<<dim3(TDIM/128, NTOK/64), 256, 0, stream>>>(xb, Wab, b_attn, Qb, Kb, Vt);
    fattn<<<NB*NHEAD*32, 64, 0, stream>>>(Qb, Kb, Vt, ctxb);
    mm_attnproj<<<dim3(DM/64, NTOK/64), 256, 0, stream>>>(ctxb, Wapb, b_aproj, hidden, hs);
    ln_router<<<NTOK, 256, 0, stream>>>(hs, ln2_g, ln2_b, w_rout, xb,
                                        cnt, expTok, tokE, tokPos, tokGate);
    offsets_kernel<<<1, 64, 0, stream>>>(cnt, offE);
    mm_fc<<<dim3(FF/128, NTOK/128, NEXP), 256, 0, stream>>>(xb, Wfcb, b_fc, expTok, cnt, offE, H);
    mm_proj<<<dim3((DM/128)*2, NTOK/64, NEXP), 256, 0, stream>>>(H, Wprb, cnt, offE, Yp);
    combine_kernel<<<NTOK, 256, 0, stream>>>(hs, Yp, b_proj, tokE, tokPos, tokGate, offE, out);
}